// Round 1
// baseline (184.478 us; speedup 1.0000x reference)
//
#include <hip/hip_runtime.h>
#include <hip/hip_bf16.h>

// ---------------------------------------------------------------------------
// KroneNet fused kernel for MI355X (gfx950)
// out[i][j] = softmax_j( s_a[i] * t_j[i] ),
//   s_a = w3a . relu(w2a . relu(w1a . x_a + b1a) + b2a) + b3a          (1 dim)
//   t_j = w3b_j . relu(w2b . relu(w1b . x_b + b1b) + b2b) + b3b_j      (3 dims)
// Layer-2 GEMMs (128x128, K=128) run on bf16 MFMA 16x16x32 with fp32 acc.
// ---------------------------------------------------------------------------

#define BTOT 262144
#define SETS 2
#define NBLK (BTOT / (128 * SETS))   // 1024 blocks, 256 samples each

typedef __attribute__((ext_vector_type(4))) float floatx4;
typedef __attribute__((ext_vector_type(8))) short bf16x8;

// workspace / LDS layout (bytes), identical in d_ws and shared memory
#define OFF_W2  0          // 2 paths * 4 ksteps * 8 ntiles * 64 lanes * 8 bf16 = 65536
#define OFF_W1  65536      // 2 paths * 128 * float4 {w0, w1, b1, 0}   = 4096
#define OFF_B2  69632      // 2 paths * 128 * float                    = 1024
#define OFF_W3A 70656      // 128 * float                              = 512
#define OFF_W3B 71168      // 3 * 128 * float                          = 1536
#define OFF_B3  72704      // {b3a, b3b0, b3b1, b3b2}                  = 16
#define WS_TOTAL 72720     // multiple of 16

static __device__ __forceinline__ short f2bf(float f) {
    __hip_bfloat16 h = __float2bfloat16(f);
    return __builtin_bit_cast(short, h);
}

// ---------------------------------------------------------------------------
// Pack kernel: 64 blocks x 256 threads. Block b packs one (path, kstep, ntile)
// fragment group of W2 into MFMA B-fragment order; block 0 also packs smalls.
// B-frag layout for mfma_f32_16x16x32_bf16: lane holds B[k=quad*8+j][n=col].
// ---------------------------------------------------------------------------
__global__ void pack_kernel(const float* __restrict__ w1a, const float* __restrict__ w1b,
                            const float* __restrict__ b1a, const float* __restrict__ b1b,
                            const float* __restrict__ w2a, const float* __restrict__ w2b,
                            const float* __restrict__ b2a, const float* __restrict__ b2b,
                            const float* __restrict__ w3a, const float* __restrict__ w3b,
                            const float* __restrict__ b3a, const float* __restrict__ b3b,
                            unsigned char* __restrict__ ws) {
    const int b = blockIdx.x;
    const int tid = threadIdx.x;
    const int path = b >> 5;
    const int r = b & 31;
    const int s = r >> 3;      // k-step (32 k's each)
    const int t = r & 7;       // n-tile (16 n's each)
    const float* w2 = path ? w2b : w2a;
    unsigned short* pk = (unsigned short*)(ws + OFF_W2 + path * 32768 + ((s * 8 + t) * 64) * 16);
    #pragma unroll
    for (int q = 0; q < 2; ++q) {
        int e = tid * 2 + q;           // 512 bf16 elems per fragment group
        int l = e >> 3, j = e & 7;
        int n = t * 16 + (l & 15);
        int k = s * 32 + ((l >> 4) * 8) + j;
        pk[e] = (unsigned short)f2bf(w2[n * 128 + k]);
    }
    if (b == 0) {
        // w1 as float4 {w0, w1, b1, 0} per k-feature, both paths (256 entries)
        {
            int pth = tid >> 7, k = tid & 127;
            const float* w1 = pth ? w1b : w1a;
            const float* b1 = pth ? b1b : b1a;
            ((float4*)(ws + OFF_W1))[tid] = make_float4(w1[2 * k], w1[2 * k + 1], b1[k], 0.f);
            ((float*)(ws + OFF_B2))[tid] = (pth ? b2b : b2a)[k];
        }
        if (tid < 128) ((float*)(ws + OFF_W3A))[tid] = w3a[tid];
        for (int i = tid; i < 384; i += 256) ((float*)(ws + OFF_W3B))[i] = w3b[i];
        if (tid == 0) {
            float* d = (float*)(ws + OFF_B3);
            d[0] = b3a[0]; d[1] = b3b[0]; d[2] = b3b[1]; d[3] = b3b[2];
        }
    }
}

// ---------------------------------------------------------------------------
// Main kernel: 1024 blocks x 256 threads (4 waves). Waves 0,1 -> path a,
// waves 2,3 -> path b. Each wave: 64 samples (4 M-tiles of 16) per set.
// ---------------------------------------------------------------------------
__global__ __launch_bounds__(256, 2)
void krone_main(const float* __restrict__ x, const unsigned char* __restrict__ ws,
                float* __restrict__ out) {
    __shared__ __align__(16) unsigned char smem[WS_TOTAL];
    __shared__ float4 sEx[128];   // per-sample exchange: {s_a, t0, t1, t2}

    const int tid = threadIdx.x;
    // cooperative copy of packed weights (L2-resident) into LDS
    {
        const float4* src = (const float4*)ws;
        float4* dst = (float4*)smem;
        for (int i = tid; i < WS_TOTAL / 16; i += 256) dst[i] = src[i];
    }
    __syncthreads();

    const int lane = tid & 63;
    const int wave = tid >> 6;
    const int quad = lane >> 4;
    const int col  = lane & 15;
    const int path = wave >> 1;          // 0 = a, 1 = b
    const int sb   = (wave & 1) * 64;    // sample base within 128-sample set

    const bf16x8* W2f = (const bf16x8*)(smem + OFF_W2 + path * 32768);
    const float4* W1  = (const float4*)(smem + OFF_W1) + path * 128;
    const float*  B2  = (const float*)(smem + OFF_B2) + path * 128;
    const float*  W3A = (const float*)(smem + OFF_W3A);
    const float*  W3B = (const float*)(smem + OFF_W3B);
    const float*  B3  = (const float*)(smem + OFF_B3);
    const float2* xp  = (const float2*)x + (long)path * BTOT;

    for (int it = 0; it < SETS; ++it) {
        const long bs = ((long)blockIdx.x * SETS + it) * 128;

        // x for this wave's 4 M-tiles (sample = bs + sb + mt*16 + col)
        float2 xv[4];
        #pragma unroll
        for (int mt = 0; mt < 4; ++mt)
            xv[mt] = xp[bs + sb + mt * 16 + col];

        floatx4 acc[8][4];
        #pragma unroll
        for (int t = 0; t < 8; ++t)
            #pragma unroll
            for (int mt = 0; mt < 4; ++mt)
                acc[t][mt] = (floatx4){0.f, 0.f, 0.f, 0.f};

        #pragma unroll
        for (int s = 0; s < 4; ++s) {
            // Build A-fragments on the fly: lane holds A[m=col][k=s*32+quad*8+j]
            bf16x8 af[4];
            #pragma unroll
            for (int j = 0; j < 8; ++j) {
                float4 c = W1[s * 32 + quad * 8 + j];   // {w0, w1, b1, 0} for this k
                #pragma unroll
                for (int mt = 0; mt < 4; ++mt) {
                    float h = fmaf(xv[mt].x, c.x, fmaf(xv[mt].y, c.y, c.z));
                    h = fmaxf(h, 0.f);
                    af[mt][j] = f2bf(h);
                }
            }
            #pragma unroll
            for (int t = 0; t < 8; ++t) {
                bf16x8 bf = W2f[(s * 8 + t) * 64 + lane];
                #pragma unroll
                for (int mt = 0; mt < 4; ++mt)
                    acc[t][mt] = __builtin_amdgcn_mfma_f32_16x16x32_bf16(
                        af[mt], bf, acc[t][mt], 0, 0, 0);
            }
        }

        // Epilogue: h2 = relu(acc + b2); layer-3 dot over n; C layout:
        // value (t, mt, r) belongs to sample (sb + mt*16 + quad*4 + r), n = t*16+col.
        if (path == 0) {
            float part[4][4] = {};
            #pragma unroll
            for (int t = 0; t < 8; ++t) {
                int n = t * 16 + col;
                float b2n = B2[n], w3n = W3A[n];
                #pragma unroll
                for (int mt = 0; mt < 4; ++mt)
                    #pragma unroll
                    for (int r = 0; r < 4; ++r) {
                        float h = fmaxf(acc[t][mt][r] + b2n, 0.f);
                        part[mt][r] = fmaf(w3n, h, part[mt][r]);
                    }
            }
            #pragma unroll
            for (int mt = 0; mt < 4; ++mt)
                #pragma unroll
                for (int r = 0; r < 4; ++r) {
                    float v = part[mt][r];
                    v += __shfl_xor(v, 1);  v += __shfl_xor(v, 2);
                    v += __shfl_xor(v, 4);  v += __shfl_xor(v, 8);
                    part[mt][r] = v;
                }
            if (col < 4) {
                float b3a_ = B3[0];
                #pragma unroll
                for (int mt = 0; mt < 4; ++mt) {
                    int sl = sb + mt * 16 + quad * 4 + col;
                    sEx[sl].x = part[mt][col] + b3a_;
                }
            }
        } else {
            float part[3][4][4] = {};
            #pragma unroll
            for (int t = 0; t < 8; ++t) {
                int n = t * 16 + col;
                float b2n = B2[n];
                float w30 = W3B[n], w31 = W3B[128 + n], w32 = W3B[256 + n];
                #pragma unroll
                for (int mt = 0; mt < 4; ++mt)
                    #pragma unroll
                    for (int r = 0; r < 4; ++r) {
                        float h = fmaxf(acc[t][mt][r] + b2n, 0.f);
                        part[0][mt][r] = fmaf(w30, h, part[0][mt][r]);
                        part[1][mt][r] = fmaf(w31, h, part[1][mt][r]);
                        part[2][mt][r] = fmaf(w32, h, part[2][mt][r]);
                    }
            }
            #pragma unroll
            for (int jj = 0; jj < 3; ++jj)
                #pragma unroll
                for (int mt = 0; mt < 4; ++mt)
                    #pragma unroll
                    for (int r = 0; r < 4; ++r) {
                        float v = part[jj][mt][r];
                        v += __shfl_xor(v, 1);  v += __shfl_xor(v, 2);
                        v += __shfl_xor(v, 4);  v += __shfl_xor(v, 8);
                        part[jj][mt][r] = v;
                    }
            if (col < 4) {
                float b30 = B3[1], b31 = B3[2], b32 = B3[3];
                #pragma unroll
                for (int mt = 0; mt < 4; ++mt) {
                    int sl = sb + mt * 16 + quad * 4 + col;
                    sEx[sl].y = part[0][mt][col] + b30;
                    sEx[sl].z = part[1][mt][col] + b31;
                    sEx[sl].w = part[2][mt][col] + b32;
                }
            }
        }
        __syncthreads();

        if (tid < 128) {
            float4 v = sEx[tid];
            float y0 = v.x * v.y, y1 = v.x * v.z, y2 = v.x * v.w;
            float m = fmaxf(y0, fmaxf(y1, y2));
            float e0 = __expf(y0 - m), e1 = __expf(y1 - m), e2 = __expf(y2 - m);
            float rs = 1.f / (e0 + e1 + e2);
            long o = (bs + tid) * 3;
            out[o]     = e0 * rs;
            out[o + 1] = e1 * rs;
            out[o + 2] = e2 * rs;
        }
        __syncthreads();   // protect sEx reuse in next set
    }
}

extern "C" void kernel_launch(void* const* d_in, const int* in_sizes, int n_in,
                              void* d_out, int out_size, void* d_ws, size_t ws_size,
                              hipStream_t stream) {
    const float* x   = (const float*)d_in[0];
    const float* w1a = (const float*)d_in[1];
    const float* w1b = (const float*)d_in[2];
    const float* b1a = (const float*)d_in[3];
    const float* b1b = (const float*)d_in[4];
    const float* w2a = (const float*)d_in[5];
    const float* w2b = (const float*)d_in[6];
    const float* b2a = (const float*)d_in[7];
    const float* b2b = (const float*)d_in[8];
    const float* w3a = (const float*)d_in[9];
    const float* w3b = (const float*)d_in[10];
    const float* b3a = (const float*)d_in[11];
    const float* b3b = (const float*)d_in[12];
    unsigned char* ws = (unsigned char*)d_ws;
    float* out = (float*)d_out;

    pack_kernel<<<64, 256, 0, stream>>>(w1a, w1b, b1a, b1b, w2a, w2b,
                                        b2a, b2b, w3a, w3b, b3a, b3b, ws);
    krone_main<<<NBLK, 256, 0, stream>>>(x, ws, out);
}

// Round 2
// 132.655 us; speedup vs baseline: 1.3907x; 1.3907x over previous
//
#include <hip/hip_runtime.h>
#include <hip/hip_bf16.h>

// ---------------------------------------------------------------------------
// KroneNet fused kernel v2 for MI355X (gfx950)
// out[i][j] = softmax_j( s_a[i] * t_j[i] )
// Round-1 lesson: dynamic register indexing (part[mt][col]) demoted arrays to
// scratch -> 27 MB HBM scratch traffic, 85% stall. v2: static-index select
// trees, barrier-free main loop (each wave owns both paths for 32 samples),
// v_perm-based bf16 pair packing.
// ---------------------------------------------------------------------------

#define BTOT 262144
#define NBLK (BTOT / 256)   // 1024 blocks x 256 samples

typedef __attribute__((ext_vector_type(4))) float floatx4;
typedef __attribute__((ext_vector_type(8))) short bf16x8;
typedef __attribute__((ext_vector_type(4))) int  intx4;

// workspace / LDS layout (bytes)
#define OFF_W2  0          // 2 paths * 4 ksteps * 8 ntiles * 64 lanes * 16B = 65536
#define OFF_W1  65536      // 2 paths * 128 * float4 {w0, w1, b1, 0}  = 4096
#define OFF_B2  69632      // 2 paths * 128 * float                   = 1024
#define OFF_W3A 70656      // 128 * float                             = 512
#define OFF_W3B 71168      // 3 * 128 * float                         = 1536
#define OFF_B3  72704      // {b3a, b3b0, b3b1, b3b2}                 = 16
#define WS_TOTAL 72720

static __device__ __forceinline__ short f2bf(float f) {
    __hip_bfloat16 h = __float2bfloat16(f);
    return __builtin_bit_cast(short, h);
}

// pack two fp32 -> one dword of two bf16 (round-half-up), 3 VALU ops
static __device__ __forceinline__ int pack2bf(float lo, float hi) {
    unsigned a = __builtin_bit_cast(unsigned, lo) + 0x8000u;
    unsigned b = __builtin_bit_cast(unsigned, hi) + 0x8000u;
    return (int)__builtin_amdgcn_perm(b, a, 0x07060302u); // {b.hi16, a.hi16}
}

// compile-time-indexed 4-way select (NO dynamic register indexing!)
#define SEL4(a0, a1, a2, a3, i) \
    ((i) == 0 ? (a0) : (i) == 1 ? (a1) : (i) == 2 ? (a2) : (a3))

static __device__ __forceinline__ float redcol(float v) {
    v += __shfl_xor(v, 1); v += __shfl_xor(v, 2);
    v += __shfl_xor(v, 4); v += __shfl_xor(v, 8);
    return v;
}

// ---------------------------------------------------------------------------
// Pack kernel (unchanged from v1, verified correct): B-fragment order
// lane holds B[k = quad*8 + j][n = col] for mfma_f32_16x16x32_bf16.
// ---------------------------------------------------------------------------
__global__ void pack_kernel(const float* __restrict__ w1a, const float* __restrict__ w1b,
                            const float* __restrict__ b1a, const float* __restrict__ b1b,
                            const float* __restrict__ w2a, const float* __restrict__ w2b,
                            const float* __restrict__ b2a, const float* __restrict__ b2b,
                            const float* __restrict__ w3a, const float* __restrict__ w3b,
                            const float* __restrict__ b3a, const float* __restrict__ b3b,
                            unsigned char* __restrict__ ws) {
    const int b = blockIdx.x;
    const int tid = threadIdx.x;
    const int path = b >> 5;
    const int r = b & 31;
    const int s = r >> 3;
    const int t = r & 7;
    const float* w2 = path ? w2b : w2a;
    unsigned short* pk = (unsigned short*)(ws + OFF_W2 + path * 32768 + ((s * 8 + t) * 64) * 16);
    #pragma unroll
    for (int q = 0; q < 2; ++q) {
        int e = tid * 2 + q;
        int l = e >> 3, j = e & 7;
        int n = t * 16 + (l & 15);
        int k = s * 32 + ((l >> 4) * 8) + j;
        pk[e] = (unsigned short)f2bf(w2[n * 128 + k]);
    }
    if (b == 0) {
        {
            int pth = tid >> 7, k = tid & 127;
            const float* w1 = pth ? w1b : w1a;
            const float* b1 = pth ? b1b : b1a;
            ((float4*)(ws + OFF_W1))[tid] = make_float4(w1[2 * k], w1[2 * k + 1], b1[k], 0.f);
            ((float*)(ws + OFF_B2))[tid] = (pth ? b2b : b2a)[k];
        }
        if (tid < 128) ((float*)(ws + OFF_W3A))[tid] = w3a[tid];
        for (int i = tid; i < 384; i += 256) ((float*)(ws + OFF_W3B))[i] = w3b[i];
        if (tid == 0) {
            float* d = (float*)(ws + OFF_B3);
            d[0] = b3a[0]; d[1] = b3b[0]; d[2] = b3b[1]; d[3] = b3b[2];
        }
    }
}

// ---------------------------------------------------------------------------
// Main kernel: 1024 blocks x 256 threads (4 waves). Each wave computes BOTH
// paths for its own 32 samples per chunk (2 chunks). Barrier-free main loop;
// per-wave LDS exchange pairs s_a with t_j (same-wave lgkmcnt ordering).
// ---------------------------------------------------------------------------
__global__ __launch_bounds__(256, 2)
void krone_main(const float* __restrict__ x, const unsigned char* __restrict__ ws,
                float* __restrict__ out) {
    __shared__ __align__(16) unsigned char smem[WS_TOTAL];
    __shared__ float4 sEx[4][32];

    const int tid = threadIdx.x;
    {
        const float4* src = (const float4*)ws;
        float4* dst = (float4*)smem;
        for (int i = tid; i < WS_TOTAL / 16; i += 256) dst[i] = src[i];
    }
    __syncthreads();

    const int lane = tid & 63;
    const int wave = tid >> 6;
    const int quad = lane >> 4;
    const int col  = lane & 15;

    const bf16x8* W2A = (const bf16x8*)(smem + OFF_W2);
    const bf16x8* W2B = (const bf16x8*)(smem + OFF_W2 + 32768);
    const float4* W1A = (const float4*)(smem + OFF_W1);
    const float4* W1B = W1A + 128;
    const float*  B2A = (const float*)(smem + OFF_B2);
    const float*  B2B = B2A + 128;
    const float*  W3A = (const float*)(smem + OFF_W3A);
    const float*  W3B = (const float*)(smem + OFF_W3B);
    const float*  B3  = (const float*)(smem + OFF_B3);
    const float2* xA  = (const float2*)x;
    const float2* xB  = xA + BTOT;

    #pragma unroll
    for (int c = 0; c < 2; ++c) {
        const int base = blockIdx.x * 256 + wave * 64 + c * 32;

        float2 xa[2], xb[2];
        #pragma unroll
        for (int mt = 0; mt < 2; ++mt) {
            xa[mt] = xA[base + mt * 16 + col];
            xb[mt] = xB[base + mt * 16 + col];
        }

        floatx4 accA[8][2], accB[8][2];
        #pragma unroll
        for (int t = 0; t < 8; ++t)
            #pragma unroll
            for (int mt = 0; mt < 2; ++mt) {
                accA[t][mt] = (floatx4){0.f, 0.f, 0.f, 0.f};
                accB[t][mt] = (floatx4){0.f, 0.f, 0.f, 0.f};
            }

        #pragma unroll
        for (int s = 0; s < 4; ++s) {
            // A-fragments on the fly: lane holds A[m=col][k=s*32+quad*8+j]
            intx4 afA[2], afB[2];
            #pragma unroll
            for (int j2 = 0; j2 < 4; ++j2) {
                float4 a0 = W1A[s * 32 + quad * 8 + 2 * j2];
                float4 a1 = W1A[s * 32 + quad * 8 + 2 * j2 + 1];
                float4 b0 = W1B[s * 32 + quad * 8 + 2 * j2];
                float4 b1 = W1B[s * 32 + quad * 8 + 2 * j2 + 1];
                #pragma unroll
                for (int mt = 0; mt < 2; ++mt) {
                    float ha0 = fmaxf(fmaf(xa[mt].x, a0.x, fmaf(xa[mt].y, a0.y, a0.z)), 0.f);
                    float ha1 = fmaxf(fmaf(xa[mt].x, a1.x, fmaf(xa[mt].y, a1.y, a1.z)), 0.f);
                    float hb0 = fmaxf(fmaf(xb[mt].x, b0.x, fmaf(xb[mt].y, b0.y, b0.z)), 0.f);
                    float hb1 = fmaxf(fmaf(xb[mt].x, b1.x, fmaf(xb[mt].y, b1.y, b1.z)), 0.f);
                    afA[mt][j2] = pack2bf(ha0, ha1);
                    afB[mt][j2] = pack2bf(hb0, hb1);
                }
            }
            #pragma unroll
            for (int t = 0; t < 8; ++t) {
                bf16x8 bfa = W2A[(s * 8 + t) * 64 + lane];
                bf16x8 bfb = W2B[(s * 8 + t) * 64 + lane];
                #pragma unroll
                for (int mt = 0; mt < 2; ++mt) {
                    accA[t][mt] = __builtin_amdgcn_mfma_f32_16x16x32_bf16(
                        __builtin_bit_cast(bf16x8, afA[mt]), bfa, accA[t][mt], 0, 0, 0);
                    accB[t][mt] = __builtin_amdgcn_mfma_f32_16x16x32_bf16(
                        __builtin_bit_cast(bf16x8, afB[mt]), bfb, accB[t][mt], 0, 0, 0);
                }
            }
        }

        // Epilogue. C layout: (t, mt, r) -> sample mt*16 + quad*4 + r, n = t*16+col.
        float pa[2][4]  = {};
        float pb0[2][4] = {}, pb1[2][4] = {}, pb2[2][4] = {};
        #pragma unroll
        for (int t = 0; t < 8; ++t) {
            int n = t * 16 + col;
            float b2a = B2A[n], w3a = W3A[n];
            float b2b = B2B[n];
            float w30 = W3B[n], w31 = W3B[128 + n], w32 = W3B[256 + n];
            #pragma unroll
            for (int mt = 0; mt < 2; ++mt)
                #pragma unroll
                for (int r = 0; r < 4; ++r) {
                    float ha = fmaxf(accA[t][mt][r] + b2a, 0.f);
                    pa[mt][r] = fmaf(w3a, ha, pa[mt][r]);
                    float hb = fmaxf(accB[t][mt][r] + b2b, 0.f);
                    pb0[mt][r] = fmaf(w30, hb, pb0[mt][r]);
                    pb1[mt][r] = fmaf(w31, hb, pb1[mt][r]);
                    pb2[mt][r] = fmaf(w32, hb, pb2[mt][r]);
                }
        }
        #pragma unroll
        for (int mt = 0; mt < 2; ++mt)
            #pragma unroll
            for (int r = 0; r < 4; ++r) {
                pa[mt][r]  = redcol(pa[mt][r]);
                pb0[mt][r] = redcol(pb0[mt][r]);
                pb1[mt][r] = redcol(pb1[mt][r]);
                pb2[mt][r] = redcol(pb2[mt][r]);
            }

        if (col < 4) {
            float b3a = B3[0], b30 = B3[1], b31 = B3[2], b32 = B3[3];
            #pragma unroll
            for (int mt = 0; mt < 2; ++mt) {
                int sl = mt * 16 + quad * 4 + col;
                float va = SEL4(pa[mt][0],  pa[mt][1],  pa[mt][2],  pa[mt][3],  col) + b3a;
                float v0 = SEL4(pb0[mt][0], pb0[mt][1], pb0[mt][2], pb0[mt][3], col) + b30;
                float v1 = SEL4(pb1[mt][0], pb1[mt][1], pb1[mt][2], pb1[mt][3], col) + b31;
                float v2 = SEL4(pb2[mt][0], pb2[mt][1], pb2[mt][2], pb2[mt][3], col) + b32;
                sEx[wave][sl] = make_float4(va, v0, v1, v2);
            }
        }
        // same-wave LDS RAW: ordered by lgkmcnt, no barrier needed
        if (lane < 32) {
            float4 v = sEx[wave][lane];
            float y0 = v.x * v.y, y1 = v.x * v.z, y2 = v.x * v.w;
            float m = fmaxf(y0, fmaxf(y1, y2));
            float e0 = __expf(y0 - m), e1 = __expf(y1 - m), e2 = __expf(y2 - m);
            float rs = 1.f / (e0 + e1 + e2);
            long o = (long)(base + lane) * 3;
            out[o]     = e0 * rs;
            out[o + 1] = e1 * rs;
            out[o + 2] = e2 * rs;
        }
    }
}

extern "C" void kernel_launch(void* const* d_in, const int* in_sizes, int n_in,
                              void* d_out, int out_size, void* d_ws, size_t ws_size,
                              hipStream_t stream) {
    const float* x   = (const float*)d_in[0];
    const float* w1a = (const float*)d_in[1];
    const float* w1b = (const float*)d_in[2];
    const float* b1a = (const float*)d_in[3];
    const float* b1b = (const float*)d_in[4];
    const float* w2a = (const float*)d_in[5];
    const float* w2b = (const float*)d_in[6];
    const float* b2a = (const float*)d_in[7];
    const float* b2b = (const float*)d_in[8];
    const float* w3a = (const float*)d_in[9];
    const float* w3b = (const float*)d_in[10];
    const float* b3a = (const float*)d_in[11];
    const float* b3b = (const float*)d_in[12];
    unsigned char* ws = (unsigned char*)d_ws;
    float* out = (float*)d_out;

    pack_kernel<<<64, 256, 0, stream>>>(w1a, w1b, b1a, b1b, w2a, w2b,
                                        b2a, b2b, w3a, w3b, b3a, b3b, ws);
    krone_main<<<NBLK, 256, 0, stream>>>(x, ws, out);
}